// Round 5
// baseline (308.026 us; speedup 1.0000x reference)
//
#include <hip/hip_runtime.h>
#include <math.h>

typedef float v4f __attribute__((ext_vector_type(4)));
typedef float v2f __attribute__((ext_vector_type(2)));

// physical constants (match reference, f32)
#define RTF       (8.3144621f / 96487.0f)   // R/F
#define VOLS_     2.2e-06f                  // 0.1*VOL
#define VOLB_     1.98e-05f                 // VOL - VOLS
#define INV_TDIFF (1.0f / 7.0e6f)

#define LUT_N 4096
#define BLOCK 256
#define GRID  2048                           // 8 persistent blocks per CU
// d_ws layout: [0, 32KB): lutJ2 (v2f per entry: {1/(2J0(x_i)), 1/(2J0(x_{i+1}))})
//              [32KB, 96KB): lutO4 (v4f per entry: {mlp(x_i), rtfLog(x_i), mlp(x_{i+1}), rtfLog(x_{i+1})})

__device__ __forceinline__ float asinh_pos(float x) {
    // x >= 0 here (current i in [1,3] A)
    return __logf(x + sqrtf(fmaf(x, x, 1.0f)));
}

// ---------------- LUT build helpers ----------------
__device__ __forceinline__ float jval(float x) {
    // 1/(2*J0): J0 = 1e-18 + 20000*sqrt(x*(1-x))
    float j0 = 1e-18f + 20000.0f * sqrtf(fmaxf(x * (1.0f - x), 0.0f));
    return 1.0f / (2.0f * j0);
}

__device__ __forceinline__ void mlp_log_eval(
    float x,
    const float* __restrict__ Wp0, const float* __restrict__ bp0,
    const float* __restrict__ Wp2, const float* __restrict__ bp2,
    const float* __restrict__ Wp4, const float* __restrict__ bp4,
    float* mlp_out, float* log_out)
{
    float h1[8];
#pragma unroll
    for (int j = 0; j < 8; j++)
        h1[j] = tanhf(fmaf(x, Wp0[j], bp0[j]));
    float mlp = bp4[0];
#pragma unroll
    for (int k = 0; k < 4; k++) {
        float a = bp2[k];
#pragma unroll
        for (int j = 0; j < 8; j++)
            a = fmaf(h1[j], Wp2[k * 8 + j], a);
        mlp = fmaf(tanhf(a), Wp4[k], mlp);
    }
    *mlp_out = mlp;
    // (R/F) * log(clip((1-x)/x, 1e-18, 1e18))
    float r = fminf(fmaxf((1.0f - x) / fmaxf(x, 1e-30f), 1e-18f), 1e18f);
    *log_out = RTF * logf(r);
}

// ---------------- LUT build kernel (runs every launch; 16 blocks, trivial cost) ----------------
__global__ __launch_bounds__(256) void build_lut_kernel(
    const float* __restrict__ Wp0, const float* __restrict__ bp0,
    const float* __restrict__ Wp2, const float* __restrict__ bp2,
    const float* __restrict__ Wp4, const float* __restrict__ bp4,
    v2f* __restrict__ lutJ2, v4f* __restrict__ lutO4)
{
    int idx = blockIdx.x * blockDim.x + threadIdx.x;
    if (idx >= LUT_N) return;
    const float dx = 1.0f / (float)(LUT_N - 1);
    float x0 = (float)idx * dx;
    float x1 = fminf(x0 + dx, 1.0f);

    v2f j; j.x = jval(x0); j.y = jval(x1);
    lutJ2[idx] = j;

    float m0, l0, m1, l1;
    mlp_log_eval(x0, Wp0, bp0, Wp2, bp2, Wp4, bp4, &m0, &l0);
    mlp_log_eval(x1, Wp0, bp0, Wp2, bp2, Wp4, bp4, &m1, &l1);
    v4f o; o.x = m0; o.y = l0; o.z = m1; o.w = l1;
    lutO4[idx] = o;
}

// ---------------- main kernel: persistent blocks, grid-stride, 1 row/iteration ----------------
__global__ __launch_bounds__(BLOCK) void battery_cell_kernel(
    const float* __restrict__ inp,   // [B]
    const float* __restrict__ st,    // [B,8]
    const float* __restrict__ qMaxp, // [B]
    const float* __restrict__ Rop,   // [B]
    const float* __restrict__ Wn,    // [1,1]
    const float* __restrict__ bn,    // [1]
    const v2f*   __restrict__ lutJ2, // [LUT_N]
    const v4f*   __restrict__ lutO4, // [LUT_N]
    float* __restrict__ outV,        // [B]
    float* __restrict__ outX,        // [B,8]
    int B)
{
    const v4f* st4 = (const v4f*)st;
    v4f* ox4 = (v4f*)outX;
    float wn = Wn[0], wbn = bn[0];

    int stride = GRID * BLOCK;
    for (int b = blockIdx.x * BLOCK + threadIdx.x; b < B; b += stride) {
        // ---- coalesced input loads (per-instruction lane-unit/32B stride) ----
        v4f s0 = st4[2 * b];
        v4f s1 = st4[2 * b + 1];
        float i  = inp[b];
        float qm = qMaxp[b];
        float ro = Rop[b];

        float Tb  = s0.x, Vo  = s0.y, Vsn = s0.z, Vsp = s0.w;
        float qnB = s1.x, qnS = s1.y, qpB = s1.z, qpS = s1.w;

        // ---- getNextState ----
        float invq = __fdividef(1.0f, qm * 1000.0f);   // 1/qSMax

        float xpS = fminf(fmaxf(qpS * invq, 1e-18f), 1.0f);
        float xnS = fminf(fmaxf(qnS * invq, 1e-18f), 1.0f);

        // paired-LUT lerp for 1/(2*J0): one 8B gather per lookup
        float tn = xnS * (float)(LUT_N - 1);
        float tp = xpS * (float)(LUT_N - 1);
        int in0 = min((int)tn, LUT_N - 2);
        int ip0 = min((int)tp, LUT_N - 2);
        float fn = tn - (float)in0;
        float fp = tp - (float)ip0;
        v2f jn = lutJ2[in0];
        v2f jp = lutJ2[ip0];
        float inv2Jn = fmaf(fn, jn.y - jn.x, jn.x);
        float inv2Jp = fmaf(fp, jp.y - jp.x, jp.x);

        float qdotn = (qnB * (1.0f / VOLB_) - qnS * (1.0f / VOLS_)) * INV_TDIFF;
        float qdotp = (qpB * (1.0f / VOLB_) - qpS * (1.0f / VOLS_)) * INV_TDIFF;

        float Jn     = i * 5000.0f;             // i/SN (== i/SP)
        float VoNom  = i * ro * 10.0f;
        float coef   = RTF * Tb * 2.0f;         // R*Tb/F/ALPHA
        float VsnNom = coef * asinh_pos(Jn * inv2Jn);
        float VspNom = coef * asinh_pos(Jn * inv2Jp);

        float Vo2  = Vo  + (VoNom  - Vo ) * 0.1f;
        float Vsn2 = Vsn + (VsnNom - Vsn) * (1.0f / 90.0f);
        float Vsp2 = Vsp + (VspNom - Vsp) * (1.0f / 90.0f);
        float qnB2 = qnB - qdotn;
        float qnS2 = qnS + qdotn - i;
        float qpB2 = qpB - qdotp;
        float qpS2 = qpS + i + qdotp;

        // ---- getNextOutput (on XNew) ----
        float xp = qpS2 * invq;
        float xn = qnS2 * invq;

        float tpo = fminf(fmaxf(xp, 0.0f), 1.0f) * (float)(LUT_N - 1);
        float tno = fminf(fmaxf(xn, 0.0f), 1.0f) * (float)(LUT_N - 1);
        int ipo = min((int)tpo, LUT_N - 2);
        int ino = min((int)tno, LUT_N - 2);
        float fpo = tpo - (float)ipo;
        float fno = tno - (float)ino;
        v4f op = lutO4[ipo];          // {mlp_i, log_i, mlp_i1, log_i1}
        v4f on = lutO4[ino];
        float mlp_p = fmaf(fpo, op.z - op.x, op.x);
        float log_p = fmaf(fpo, op.w - op.y, op.y);
        float log_n = fmaf(fno, on.w - on.y, on.y);

        float Vep = 4.03f + Tb * log_p + mlp_p;
        float Ven = 0.01f + Tb * log_n + fmaf(xn, wn, wbn);
        float V = Vep - Ven - Vo2 - Vsn2 - Vsp2;

        // ---- plain coalesced stores (L2 write-back merges; R0/R3/R4 all show ideal WRITE_SIZE) ----
        outV[b] = V;
        v4f o0; o0.x = Tb;   o0.y = Vo2;  o0.z = Vsn2; o0.w = Vsp2;
        v4f o1; o1.x = qnB2; o1.y = qnS2; o1.z = qpB2; o1.w = qpS2;
        ox4[2 * b]     = o0;
        ox4[2 * b + 1] = o1;
    }
}

extern "C" void kernel_launch(void* const* d_in, const int* in_sizes, int n_in,
                              void* d_out, int out_size, void* d_ws, size_t ws_size,
                              hipStream_t stream) {
    const float* inp  = (const float*)d_in[0];
    const float* st   = (const float*)d_in[1];
    const float* qMax = (const float*)d_in[2];
    const float* Ro   = (const float*)d_in[3];
    const float* Wp0  = (const float*)d_in[4];
    const float* bp0  = (const float*)d_in[5];
    const float* Wp2  = (const float*)d_in[6];
    const float* bp2  = (const float*)d_in[7];
    const float* Wp4  = (const float*)d_in[8];
    const float* bp4  = (const float*)d_in[9];
    const float* Wn   = (const float*)d_in[10];
    const float* bn   = (const float*)d_in[11];

    int B = in_sizes[0];
    float* outV = (float*)d_out;
    float* outX = (float*)d_out + B;

    v2f* lutJ2 = (v2f*)d_ws;                            // 32 KB
    v4f* lutO4 = (v4f*)((char*)d_ws + LUT_N * 8);       // 64 KB

    build_lut_kernel<<<LUT_N / 256, 256, 0, stream>>>(
        Wp0, bp0, Wp2, bp2, Wp4, bp4, lutJ2, lutO4);

    battery_cell_kernel<<<GRID, BLOCK, 0, stream>>>(
        inp, st, qMax, Ro, Wn, bn, lutJ2, lutO4, outV, outX, B);
}

// Round 6
// 293.264 us; speedup vs baseline: 1.0503x; 1.0503x over previous
//
#include <hip/hip_runtime.h>
#include <math.h>

typedef float v4f __attribute__((ext_vector_type(4)));
typedef float v2f __attribute__((ext_vector_type(2)));

// physical constants (match reference, f32)
#define RTF       (8.3144621f / 96487.0f)   // R/F
#define VOLS_     2.2e-06f                  // 0.1*VOL
#define VOLB_     1.98e-05f                 // VOL - VOLS
#define INV_TDIFF (1.0f / 7.0e6f)

#define LUT_N 4096
#define BLOCK 256
// d_ws layout: [0, 32KB): lutJ2 (v2f per entry: {1/(2J0(x_i)), 1/(2J0(x_{i+1}))})
//              [32KB, 96KB): lutO4 (v4f per entry: {mlp(x_i), rtfLog(x_i), mlp(x_{i+1}), rtfLog(x_{i+1})})

__device__ __forceinline__ float asinh_pos(float x) {
    // x >= 0 here (current i in [1,3] A)
    return __logf(x + sqrtf(fmaf(x, x, 1.0f)));
}

// XOR swizzle in v4f(16B) units: distributes both chunk-order and row-order
// accesses across all 32 LDS banks (groups of 8 indices hit 8 distinct
// 4-bank groups). Involution: swz(swz(c)) == c.
__device__ __forceinline__ int swz(int c) { return c ^ ((c >> 1) & 7); }

// ---------------- LUT build helpers ----------------
__device__ __forceinline__ float jval(float x) {
    // 1/(2*J0): J0 = 1e-18 + 20000*sqrt(x*(1-x))
    float j0 = 1e-18f + 20000.0f * sqrtf(fmaxf(x * (1.0f - x), 0.0f));
    return 1.0f / (2.0f * j0);
}

__device__ __forceinline__ void mlp_log_eval(
    float x,
    const float* __restrict__ Wp0, const float* __restrict__ bp0,
    const float* __restrict__ Wp2, const float* __restrict__ bp2,
    const float* __restrict__ Wp4, const float* __restrict__ bp4,
    float* mlp_out, float* log_out)
{
    float h1[8];
#pragma unroll
    for (int j = 0; j < 8; j++)
        h1[j] = tanhf(fmaf(x, Wp0[j], bp0[j]));
    float mlp = bp4[0];
#pragma unroll
    for (int k = 0; k < 4; k++) {
        float a = bp2[k];
#pragma unroll
        for (int j = 0; j < 8; j++)
            a = fmaf(h1[j], Wp2[k * 8 + j], a);
        mlp = fmaf(tanhf(a), Wp4[k], mlp);
    }
    *mlp_out = mlp;
    // (R/F) * log(clip((1-x)/x, 1e-18, 1e18))
    float r = fminf(fmaxf((1.0f - x) / fmaxf(x, 1e-30f), 1e-18f), 1e18f);
    *log_out = RTF * logf(r);
}

// ---------------- LUT build kernel (runs every launch; 16 blocks, trivial cost) ----------------
__global__ __launch_bounds__(256) void build_lut_kernel(
    const float* __restrict__ Wp0, const float* __restrict__ bp0,
    const float* __restrict__ Wp2, const float* __restrict__ bp2,
    const float* __restrict__ Wp4, const float* __restrict__ bp4,
    v2f* __restrict__ lutJ2, v4f* __restrict__ lutO4)
{
    int idx = blockIdx.x * blockDim.x + threadIdx.x;
    if (idx >= LUT_N) return;
    const float dx = 1.0f / (float)(LUT_N - 1);
    float x0 = (float)idx * dx;
    float x1 = fminf(x0 + dx, 1.0f);

    v2f j; j.x = jval(x0); j.y = jval(x1);
    lutJ2[idx] = j;

    float m0, l0, m1, l1;
    mlp_log_eval(x0, Wp0, bp0, Wp2, bp2, Wp4, bp4, &m0, &l0);
    mlp_log_eval(x1, Wp0, bp0, Wp2, bp2, Wp4, bp4, &m1, &l1);
    v4f o; o.x = m0; o.y = l0; o.z = m1; o.w = l1;
    lutO4[idx] = o;
}

// ---------------- per-row physics (identical to the round-0 body) ----------------
__device__ __forceinline__ void process_row(
    v4f s0, v4f s1, float i, float qm, float ro,
    float wn, float wbn,
    const v2f* __restrict__ lutJ2, const v4f* __restrict__ lutO4,
    float& Vout, v4f& o0, v4f& o1)
{
    float Tb  = s0.x, Vo  = s0.y, Vsn = s0.z, Vsp = s0.w;
    float qnB = s1.x, qnS = s1.y, qpB = s1.z, qpS = s1.w;

    // ---- getNextState ----
    float invq = __fdividef(1.0f, qm * 1000.0f);   // 1/qSMax

    float xpS = fminf(fmaxf(qpS * invq, 1e-18f), 1.0f);
    float xnS = fminf(fmaxf(qnS * invq, 1e-18f), 1.0f);

    float tn = xnS * (float)(LUT_N - 1);
    float tp = xpS * (float)(LUT_N - 1);
    int in0 = min((int)tn, LUT_N - 2);
    int ip0 = min((int)tp, LUT_N - 2);
    float fn = tn - (float)in0;
    float fp = tp - (float)ip0;
    v2f jn = lutJ2[in0];
    v2f jp = lutJ2[ip0];
    float inv2Jn = fmaf(fn, jn.y - jn.x, jn.x);
    float inv2Jp = fmaf(fp, jp.y - jp.x, jp.x);

    float qdotn = (qnB * (1.0f / VOLB_) - qnS * (1.0f / VOLS_)) * INV_TDIFF;
    float qdotp = (qpB * (1.0f / VOLB_) - qpS * (1.0f / VOLS_)) * INV_TDIFF;

    float Jn     = i * 5000.0f;             // i/SN (== i/SP)
    float VoNom  = i * ro * 10.0f;
    float coef   = RTF * Tb * 2.0f;         // R*Tb/F/ALPHA
    float VsnNom = coef * asinh_pos(Jn * inv2Jn);
    float VspNom = coef * asinh_pos(Jn * inv2Jp);

    float Vo2  = Vo  + (VoNom  - Vo ) * 0.1f;
    float Vsn2 = Vsn + (VsnNom - Vsn) * (1.0f / 90.0f);
    float Vsp2 = Vsp + (VspNom - Vsp) * (1.0f / 90.0f);
    float qnB2 = qnB - qdotn;
    float qnS2 = qnS + qdotn - i;
    float qpB2 = qpB - qdotp;
    float qpS2 = qpS + i + qdotp;

    // ---- getNextOutput (on XNew) ----
    float xp = qpS2 * invq;
    float xn = qnS2 * invq;

    float tpo = fminf(fmaxf(xp, 0.0f), 1.0f) * (float)(LUT_N - 1);
    float tno = fminf(fmaxf(xn, 0.0f), 1.0f) * (float)(LUT_N - 1);
    int ipo = min((int)tpo, LUT_N - 2);
    int ino = min((int)tno, LUT_N - 2);
    float fpo = tpo - (float)ipo;
    float fno = tno - (float)ino;
    v4f op = lutO4[ipo];          // {mlp_i, log_i, mlp_i1, log_i1}
    v4f on = lutO4[ino];
    float mlp_p = fmaf(fpo, op.z - op.x, op.x);
    float log_p = fmaf(fpo, op.w - op.y, op.y);
    float log_n = fmaf(fno, on.w - on.y, on.y);

    float Vep = 4.03f + Tb * log_p + mlp_p;
    float Ven = 0.01f + Tb * log_n + fmaf(xn, wn, wbn);
    Vout = Vep - Ven - Vo2 - Vsn2 - Vsp2;

    o0.x = Tb;   o0.y = Vo2;  o0.z = Vsn2; o0.w = Vsp2;
    o1.x = qnB2; o1.y = qnS2; o1.z = qpB2; o1.w = qpS2;
}

// ---------------- main kernel: one-shot blocks, LDS-transposed st/outX ----------------
// Every global-memory instruction is lane-unit-stride:
//   st  : 2x global_load_dwordx4 contiguous -> LDS (swizzled) -> row reads
//   outX: row writes -> LDS (swizzled) -> 2x global_store_dwordx4 contiguous
__global__ __launch_bounds__(BLOCK) void battery_cell_kernel(
    const float* __restrict__ inp,   // [B]
    const float* __restrict__ st,    // [B,8]
    const float* __restrict__ qMaxp, // [B]
    const float* __restrict__ Rop,   // [B]
    const float* __restrict__ Wn,    // [1,1]
    const float* __restrict__ bn,    // [1]
    const v2f*   __restrict__ lutJ2, // [LUT_N]
    const v4f*   __restrict__ lutO4, // [LUT_N]
    float* __restrict__ outV,        // [B]
    float* __restrict__ outX,        // [B,8]
    int B)
{
    __shared__ v4f ldsA[2 * BLOCK];   // 8 KB staging for st
    __shared__ v4f ldsB[2 * BLOCK];   // 8 KB staging for outX

    int tid  = threadIdx.x;
    int base = blockIdx.x * BLOCK;
    float wn = Wn[0], wbn = bn[0];

    if (base + BLOCK <= B) {
        int b = base + tid;
        // scalar streams: already unit-stride, load direct (issued before staging
        // so their latency hides under the LDS transpose + barrier)
        float i  = inp[b];
        float qm = qMaxp[b];
        float ro = Rop[b];

        // ---- stage st: 2 contiguous dwordx4 loads per thread -> swizzled LDS ----
        const v4f* stG = (const v4f*)st + 2 * base;
        ldsA[swz(tid)]         = stG[tid];
        ldsA[swz(tid + BLOCK)] = stG[tid + BLOCK];
        __syncthreads();

        // ---- row reads from LDS (conflict-free by swizzle) ----
        v4f s0 = ldsA[swz(2 * tid)];
        v4f s1 = ldsA[swz(2 * tid + 1)];

        float V; v4f o0, o1;
        process_row(s0, s1, i, qm, ro, wn, wbn, lutJ2, lutO4, V, o0, o1);

        outV[b] = V;   // 4B/lane unit-stride, direct

        // ---- transpose outX back: row writes -> LDS, then contiguous stores ----
        ldsB[swz(2 * tid)]     = o0;
        ldsB[swz(2 * tid + 1)] = o1;
        __syncthreads();

        v4f* oxG = (v4f*)outX + 2 * base;
        oxG[tid]         = ldsB[swz(tid)];
        oxG[tid + BLOCK] = ldsB[swz(tid + BLOCK)];
    } else {
        // tail block (not hit for B=4M): direct per-row path, no barriers
        int b = base + tid;
        if (b < B) {
            const v4f* st4 = (const v4f*)st;
            v4f s0 = st4[2 * b];
            v4f s1 = st4[2 * b + 1];
            float V; v4f o0, o1;
            process_row(s0, s1, inp[b], qMaxp[b], Rop[b], wn, wbn,
                        lutJ2, lutO4, V, o0, o1);
            outV[b] = V;
            v4f* ox4 = (v4f*)outX;
            ox4[2 * b]     = o0;
            ox4[2 * b + 1] = o1;
        }
    }
}

extern "C" void kernel_launch(void* const* d_in, const int* in_sizes, int n_in,
                              void* d_out, int out_size, void* d_ws, size_t ws_size,
                              hipStream_t stream) {
    const float* inp  = (const float*)d_in[0];
    const float* st   = (const float*)d_in[1];
    const float* qMax = (const float*)d_in[2];
    const float* Ro   = (const float*)d_in[3];
    const float* Wp0  = (const float*)d_in[4];
    const float* bp0  = (const float*)d_in[5];
    const float* Wp2  = (const float*)d_in[6];
    const float* bp2  = (const float*)d_in[7];
    const float* Wp4  = (const float*)d_in[8];
    const float* bp4  = (const float*)d_in[9];
    const float* Wn   = (const float*)d_in[10];
    const float* bn   = (const float*)d_in[11];

    int B = in_sizes[0];
    float* outV = (float*)d_out;
    float* outX = (float*)d_out + B;

    v2f* lutJ2 = (v2f*)d_ws;                            // 32 KB
    v4f* lutO4 = (v4f*)((char*)d_ws + LUT_N * 8);       // 64 KB

    build_lut_kernel<<<LUT_N / 256, 256, 0, stream>>>(
        Wp0, bp0, Wp2, bp2, Wp4, bp4, lutJ2, lutO4);

    int grid = (B + BLOCK - 1) / BLOCK;
    battery_cell_kernel<<<grid, BLOCK, 0, stream>>>(
        inp, st, qMax, Ro, Wn, bn, lutJ2, lutO4, outV, outX, B);
}